// Round 8
// baseline (133.774 us; speedup 1.0000x reference)
//
#include <hip/hip_runtime.h>
#include <hip/hip_bf16.h>

#define N_NODES 50000
#define E_EDGES 800000
#define NHEAD 4
#define DHEAD 32
#define DOUT 128   // NHEAD*DHEAD == D_IN
#define NEG_SLOPE 0.01f
#define EPS_F 1e-16f
#define DMAX 256
#define ELP 264    // EL head pitch (words); 264%32==8 -> heads hit distinct banks
#define NB 196     // dst buckets of 256 nodes (dst>>8), 49999>>8 == 195
#define CAP 8192   // payload capacity per bucket (mean 4096, sigma 64)

typedef __attribute__((ext_vector_type(8))) short bf16x8;
typedef __attribute__((ext_vector_type(4))) float f32x4;

__device__ __forceinline__ float bf2f(unsigned short u) {
    return __uint_as_float((unsigned)u << 16);
}
__device__ __forceinline__ unsigned short f2bf(float f) {
    return __bfloat16_as_ushort(__float2bfloat16(f));   // RNE
}

// ---- edge index fetch, robust to int32 vs int64 storage ----
__device__ __forceinline__ void load_edge(const int* __restrict__ ei, int isI64,
                                          int e, int& src, int& dst) {
    if (isI64) { src = ei[2 * e]; dst = ei[2 * (E_EDGES + e)]; }
    else       { src = ei[e];     dst = ei[E_EDGES + e]; }
}

// ---- K0: weight transpose+cvt (blocks 0..255) + int64-detect (block 256) ----
__global__ __launch_bounds__(128) void k_prep(const float* __restrict__ Wp,
                                              const float* __restrict__ Ws,
                                              const int* __restrict__ ei,
                                              unsigned short* __restrict__ Wt,
                                              int* __restrict__ flag) {
    int b = blockIdx.x;
    if (b < 256) {
        int c = b, k = threadIdx.x;   // col c of [Wp|Ws], row k
        float v = (c < DOUT) ? Wp[k * DOUT + c] : Ws[k * DOUT + (c - DOUT)];
        Wt[c * DOUT + k] = f2bf(v);
    } else {
        __shared__ int cnt;
        if (threadIdx.x == 0) cnt = 0;
        __syncthreads();
        int nz = 0;
        #pragma unroll
        for (int k2 = 0; k2 < 16; ++k2) {
            int pos = (threadIdx.x + k2 * 128) * 2 + 1;   // odd int32 slots
            if (ei[pos] != 0) nz = 1;
        }
        if (nz) atomicOr(&cnt, 1);
        __syncthreads();
        if (threadIdx.x == 0) *flag = (cnt == 0) ? 1 : 0;
    }
}

// ---- K1: MFMA GEMM [hb | out] = bf16(x) @ [Wp | Ws], fused attdot epilogue ----
// 512 threads = 8 waves; wave (rw=wid&3, cw=wid>>2) does rows rw*16, col-half cw.
// Per wave: 8 nf x 4 ks = 32 MFMAs / 32 B-loads (half the R7 chain), acc = 32 VGPR.
// C/D layout: col=lane&15, row=(lane>>4)*4+reg  [learn_hip m89].
#define HBP 142    // LDS h-tile pitch in bf16
__global__ __launch_bounds__(512) void k_gemm(const float* __restrict__ x,
                                              const unsigned short* __restrict__ Wt,
                                              const float* __restrict__ att,
                                              unsigned short* __restrict__ hb,
                                              float* __restrict__ as_,
                                              float* __restrict__ ad_,
                                              float* __restrict__ out) {
    __shared__ unsigned short HB[64 * HBP];   // 18.2 KB
    const int tid = threadIdx.x;
    const int wid = tid >> 6;
    const int rw  = wid & 3;            // row tile within block
    const int cw  = wid >> 2;           // 0: h half (cols 0-127), 1: skip half
    const int l   = tid & 63;
    const int l15 = l & 15;
    const int lq  = l >> 4;
    const int rowbase = blockIdx.x * 64 + rw * 16;
    const int koff = lq * 8;

    int arow = rowbase + l15;
    if (arow > N_NODES - 1) arow = N_NODES - 1;
    const float* __restrict__ xr = x + (size_t)arow * DOUT;
    bf16x8 afr[4];
    #pragma unroll
    for (int ks = 0; ks < 4; ++ks) {
        float4 u0 = *(const float4*)(xr + ks * 32 + koff);
        float4 u1 = *(const float4*)(xr + ks * 32 + koff + 4);
        bf16x8 a;
        a[0] = (short)f2bf(u0.x); a[1] = (short)f2bf(u0.y);
        a[2] = (short)f2bf(u0.z); a[3] = (short)f2bf(u0.w);
        a[4] = (short)f2bf(u1.x); a[5] = (short)f2bf(u1.y);
        a[6] = (short)f2bf(u1.z); a[7] = (short)f2bf(u1.w);
        afr[ks] = a;
    }

    f32x4 acc[8];
    #pragma unroll
    for (int nf = 0; nf < 8; ++nf) acc[nf] = (f32x4)(0.0f);

    #pragma unroll
    for (int nf = 0; nf < 8; ++nf) {
        const unsigned short* wp = Wt + (size_t)((cw * 8 + nf) * 16 + l15) * DOUT + koff;
        #pragma unroll
        for (int ks = 0; ks < 4; ++ks) {
            bf16x8 b = *(const bf16x8*)(wp + ks * 32);
            acc[nf] = __builtin_amdgcn_mfma_f32_16x16x32_bf16(afr[ks], b, acc[nf], 0, 0, 0);
        }
    }

    if (cw == 1) {
        // skip half -> out (d_out is exactly N_NODES rows: guard)
        #pragma unroll
        for (int nf = 0; nf < 8; ++nf) {
            #pragma unroll
            for (int q = 0; q < 4; ++q) {
                int row = rowbase + lq * 4 + q;
                if (row < N_NODES)
                    out[(size_t)row * DOUT + nf * 16 + l15] = acc[nf][q];
            }
        }
    } else {
        // h half -> LDS tile (bf16)
        #pragma unroll
        for (int nf = 0; nf < 8; ++nf) {
            #pragma unroll
            for (int q = 0; q < 4; ++q) {
                int rl = rw * 16 + lq * 4 + q;
                HB[rl * HBP + nf * 16 + l15] = f2bf(acc[nf][q]);
            }
        }
    }
    __syncthreads();

    // fused attdot: threads 0..255 = 64 rows x 4 heads
    if (tid < 256) {
        int rl = tid >> 2, hd = tid & 3;
        const unsigned* HBu = (const unsigned*)HB;
        const float* a1 = att + hd * 2 * DHEAD;
        const float* a2 = a1 + DHEAD;
        float s1 = 0.0f, s2 = 0.0f;
        #pragma unroll
        for (int j = 0; j < 16; ++j) {
            unsigned u = HBu[rl * (HBP / 2) + hd * 16 + j];
            float lo = bf2f((unsigned short)(u & 0xffff));
            float hi = bf2f((unsigned short)(u >> 16));
            s1 += lo * a1[2 * j] + hi * a1[2 * j + 1];
            s2 += lo * a2[2 * j] + hi * a2[2 * j + 1];
        }
        int rowg = blockIdx.x * 64 + rl;     // as_/ad_ padded to 50048
        as_[(size_t)rowg * 4 + hd] = s1;
        ad_[(size_t)rowg * 4 + hd] = s2;
    }

    // hb global store, 16B per lane (hb padded to 50048 rows)
    {
        const unsigned* HBu = (const unsigned*)HB;
        #pragma unroll
        for (int it = 0; it < 2; ++it) {
            int idx = it * 512 + tid;        // 0..1023
            int row = idx >> 4, g = idx & 15;
            int wb = row * (HBP / 2) + g * 4;
            uint4 v;
            v.x = HBu[wb]; v.y = HBu[wb + 1]; v.z = HBu[wb + 2]; v.w = HBu[wb + 3];
            *(uint4*)(hb + ((size_t)(blockIdx.x * 64 + row)) * DOUT + g * 8) = v;
        }
    }
}

// ---- K2a: bucket partition. 256 blocks x 3125 edges. Payload (dl<<16)|src. ----
__global__ __launch_bounds__(256) void k_part(const int* __restrict__ ei,
                                              const int* __restrict__ flag,
                                              int* __restrict__ bucketCnt,
                                              unsigned* __restrict__ payload) {
    __shared__ int hist[NB];
    __shared__ int curs[NB];
    const int t = threadIdx.x;
    const int base = blockIdx.x * 3125;
    const int isI64 = *flag;

    for (int i = t; i < NB; i += 256) hist[i] = 0;
    __syncthreads();
    for (int i = t; i < 3125; i += 256) {
        int src, dst;
        load_edge(ei, isI64, base + i, src, dst);
        if ((unsigned)dst < N_NODES) atomicAdd(&hist[dst >> 8], 1);
    }
    __syncthreads();
    for (int i = t; i < NB; i += 256)
        curs[i] = atomicAdd(&bucketCnt[i], hist[i]);
    __syncthreads();
    for (int i = t; i < 3125; i += 256) {
        int src, dst;
        load_edge(ei, isI64, base + i, src, dst);
        if ((unsigned)src >= N_NODES || (unsigned)dst >= N_NODES) continue;
        int b = dst >> 8;
        int pos = atomicAdd(&curs[b], 1);
        if (pos < CAP)
            payload[((size_t)b << 13) + pos] = ((unsigned)(dst & 255) << 16) | (unsigned)src;
    }
}

// ---- K2b: per-bucket CSR build: deg/ofs (bucket-based) + srcs scatter ----
__global__ __launch_bounds__(256) void k_csr(const int* __restrict__ bucketCnt,
                                             const unsigned* __restrict__ payload,
                                             int* __restrict__ deg,
                                             int* __restrict__ ofs,
                                             int* __restrict__ srcs) {
    __shared__ int h[256];
    __shared__ int cur[256];
    __shared__ int sc[256];
    const int b = blockIdx.x;
    const int t = threadIdx.x;
    int cnt = bucketCnt[b];
    if (cnt > CAP) cnt = CAP;
    const unsigned* __restrict__ pl = payload + ((size_t)b << 13);

    h[t] = 0;
    __syncthreads();
    for (int i = t; i < cnt; i += 256) atomicAdd(&h[pl[i] >> 16], 1);
    __syncthreads();
    int v = h[t];
    sc[t] = v;
    __syncthreads();
    #pragma unroll
    for (int off = 1; off < 256; off <<= 1) {
        int u = (t >= off) ? sc[t - off] : 0;
        __syncthreads();
        sc[t] += u;
        __syncthreads();
    }
    int ex = sc[t] - v;              // exclusive local prefix
    cur[t] = ex;
    int n = (b << 8) + t;
    if (n < N_NODES) { deg[n] = v; ofs[n] = (b << 13) + ex; }
    __syncthreads();
    for (int i = t; i < cnt; i += 256) {
        unsigned p = pl[i];
        int pos = atomicAdd(&cur[p >> 16], 1);
        srcs[((size_t)b << 13) + pos] = (int)(p & 0xFFFFu);
    }
}

// ---- K3: per-node gather: 2 nodes/block, 64 thr/node, uint col-pair loads ----
__global__ __launch_bounds__(128) void k_gat(const int* __restrict__ ofs,
                                             const int* __restrict__ deg,
                                             const int* __restrict__ srcs,
                                             const float* __restrict__ as_,
                                             const float* __restrict__ ad_,
                                             const unsigned short* __restrict__ hb,
                                             float* __restrict__ out) {
    __shared__ float EL[2][NHEAD * ELP];   // 2 x 4.2 KB
    __shared__ int   SRC[2][DMAX];         // 2 x 1 KB

    const int sub = threadIdx.x >> 6;      // node slot in block
    const int k   = threadIdx.x & 63;
    const int hd  = k >> 4;
    const int l16 = k & 15;
    const int n = blockIdx.x * 2 + sub;    // 25000*2 == 50000 exactly
    const int o = ofs[n];
    const int d = deg[n];
    const unsigned* __restrict__ hbu = (const unsigned*)hb;
    float* ELn = EL[sub];
    int*   SRCn = SRC[sub];

    int fast = __syncthreads_and(d <= DMAX);   // block-uniform branch

    if (fast) {
        const float4 adv4 = *(const float4*)(ad_ + (size_t)n * 4);
        for (int e = k; e < d; e += 64) {
            int s = srcs[o + e];
            SRCn[e] = s;
            float4 a4 = *(const float4*)(as_ + (size_t)s * 4);
            float e0 = a4.x + adv4.x, e1 = a4.y + adv4.y;
            float e2 = a4.z + adv4.z, e3 = a4.w + adv4.w;
            ELn[0 * ELP + e] = (e0 > 0.0f) ? e0 : NEG_SLOPE * e0;
            ELn[1 * ELP + e] = (e1 > 0.0f) ? e1 : NEG_SLOPE * e1;
            ELn[2 * ELP + e] = (e2 > 0.0f) ? e2 : NEG_SLOPE * e2;
            ELn[3 * ELP + e] = (e3 > 0.0f) ? e3 : NEG_SLOPE * e3;
        }
        __syncthreads();
        float m = -3.4e38f;
        for (int i = l16; i < d; i += 16) m = fmaxf(m, ELn[hd * ELP + i]);
        #pragma unroll
        for (int off = 8; off; off >>= 1) m = fmaxf(m, __shfl_xor(m, off));
        float den = 0.0f;
        for (int i = l16; i < d; i += 16) {
            float p = __expf(ELn[hd * ELP + i] - m);
            ELn[hd * ELP + i] = p;
            den += p;
        }
        #pragma unroll
        for (int off = 8; off; off >>= 1) den += __shfl_xor(den, off);
        __syncthreads();
        float num0 = 0.0f, num1 = 0.0f;
        for (int i = 0; i < d; ++i) {
            float p = ELn[hd * ELP + i];
            int s = SRCn[i];
            unsigned u = hbu[(size_t)s * (DOUT / 2) + k];
            num0 = fmaf(p, bf2f((unsigned short)(u & 0xffff)), num0);
            num1 = fmaf(p, bf2f((unsigned short)(u >> 16)), num1);
        }
        float inv = 1.0f / (den + EPS_F);
        float2* op = (float2*)(out + (size_t)n * DOUT + 2 * k);
        float2 sk = *op;
        *op = make_float2(num0 * inv + sk.x, num1 * inv + sk.y);
    } else {
        const float adv = ad_[(size_t)n * 4 + hd];
        float m = -3.4e38f;
        for (int i = 0; i < d; ++i) {
            float el = as_[(size_t)srcs[o + i] * 4 + hd] + adv;
            el = (el > 0.0f) ? el : NEG_SLOPE * el;
            m = fmaxf(m, el);
        }
        float den = 0.0f, num0 = 0.0f, num1 = 0.0f;
        for (int i = 0; i < d; ++i) {
            int s = srcs[o + i];
            float el = as_[(size_t)s * 4 + hd] + adv;
            el = (el > 0.0f) ? el : NEG_SLOPE * el;
            float p = __expf(el - m);
            den += p;
            unsigned u = hbu[(size_t)s * (DOUT / 2) + k];
            num0 = fmaf(p, bf2f((unsigned short)(u & 0xffff)), num0);
            num1 = fmaf(p, bf2f((unsigned short)(u >> 16)), num1);
        }
        float inv = 1.0f / (den + EPS_F);
        float2* op = (float2*)(out + (size_t)n * DOUT + 2 * k);
        float2 sk = *op;
        *op = make_float2(num0 * inv + sk.x, num1 * inv + sk.y);
    }
}

extern "C" void kernel_launch(void* const* d_in, const int* in_sizes, int n_in,
                              void* d_out, int out_size, void* d_ws, size_t ws_size,
                              hipStream_t stream) {
    const float* x   = (const float*)d_in[0];
    const float* Wp  = (const float*)d_in[1];
    const float* att = (const float*)d_in[2];
    const float* Ws  = (const float*)d_in[3];
    const int*   ei  = (const int*)d_in[4];
    float* out = (float*)d_out;

    char* ws = (char*)d_ws;
    unsigned short* hb        = (unsigned short*)(ws);              // 12,812,288 B (50048 rows)
    unsigned short* Wt        = (unsigned short*)(ws + 12812288);   // 65,536 B
    float*          as_       = (float*)(ws + 12877824);            // 800,768 B
    float*          ad_       = (float*)(ws + 13678592);            // 800,768 B
    int*            deg       = (int*)(ws + 14479360);              // 200,704 B
    int*            ofs       = (int*)(ws + 14680064);              // 200,704 B
    unsigned*       payload   = (unsigned*)(ws + 14880768);         // 6,422,528 B
    int*            srcs      = (int*)(ws + 21303296);              // 6,422,528 B
    int*            bucketCnt = (int*)(ws + 27725824);              // 1,024 B
    int*            flag      = (int*)(ws + 27726848);

    hipMemsetAsync(bucketCnt, 0, NB * 4, stream);

    k_prep<<<257, 128, 0, stream>>>(Wp, Ws, ei, Wt, flag);
    k_gemm<<<(N_NODES + 63) / 64, 512, 0, stream>>>(x, Wt, att, hb, as_, ad_, out);
    k_part<<<256, 256, 0, stream>>>(ei, flag, bucketCnt, payload);
    k_csr<<<NB, 256, 0, stream>>>(bucketCnt, payload, deg, ofs, srcs);
    k_gat<<<N_NODES / 2, 128, 0, stream>>>(ofs, deg, srcs, as_, ad_, hb, out);
}

// Round 9
// 118.413 us; speedup vs baseline: 1.1297x; 1.1297x over previous
//
#include <hip/hip_runtime.h>
#include <hip/hip_bf16.h>

#define N_NODES 50000
#define E_EDGES 800000
#define NHEAD 4
#define DHEAD 32
#define DOUT 128   // NHEAD*DHEAD == D_IN
#define NEG_SLOPE 0.01f
#define EPS_F 1e-16f
#define DMAX 256
#define ELP 264    // EL head pitch (words); 264%32==8 -> heads hit distinct banks
#define NB 196     // dst buckets of 256 nodes (dst>>8), 49999>>8 == 195
#define CAP 8192   // payload capacity per bucket (mean 4096, sigma 64)

typedef __attribute__((ext_vector_type(8))) short bf16x8;
typedef __attribute__((ext_vector_type(4))) float f32x4;

__device__ __forceinline__ float bf2f(unsigned short u) {
    return __uint_as_float((unsigned)u << 16);
}
__device__ __forceinline__ unsigned short f2bf(float f) {
    return __bfloat16_as_ushort(__float2bfloat16(f));   // RNE
}

// ---- edge index fetch, robust to int32 vs int64 storage ----
__device__ __forceinline__ void load_edge(const int* __restrict__ ei, int isI64,
                                          int e, int& src, int& dst) {
    if (isI64) { src = ei[2 * e]; dst = ei[2 * (E_EDGES + e)]; }
    else       { src = ei[e];     dst = ei[E_EDGES + e]; }
}

// ---- K0: weights -> MFMA-fragment-ordered bf16 (blocks 0..255) + detect ----
// Wt element for (col c, k): nf=c>>4, l15=c&15, ks=k>>5, lq=(k&31)>>3, e=k&7
// addr = ((nf*4+ks)*64 + lq*16+l15)*8 + e  -> k_gemm B-load is lane-contiguous.
__global__ __launch_bounds__(128) void k_prep(const float* __restrict__ Wp,
                                              const float* __restrict__ Ws,
                                              const int* __restrict__ ei,
                                              unsigned short* __restrict__ Wt,
                                              int* __restrict__ flag) {
    int b = blockIdx.x;
    if (b < 256) {
        int c = b, k = threadIdx.x;   // col c of [Wp|Ws], row k
        float v = (c < DOUT) ? Wp[k * DOUT + c] : Ws[k * DOUT + (c - DOUT)];
        int nf = c >> 4, cl = c & 15;
        int ks = k >> 5, r = k & 31, lq = r >> 3, e = r & 7;
        Wt[(((nf * 4 + ks) << 6) + lq * 16 + cl) * 8 + e] = f2bf(v);
    } else {
        __shared__ int cnt;
        if (threadIdx.x == 0) cnt = 0;
        __syncthreads();
        int nz = 0;
        #pragma unroll
        for (int k2 = 0; k2 < 16; ++k2) {
            int pos = (threadIdx.x + k2 * 128) * 2 + 1;   // odd int32 slots
            if (ei[pos] != 0) nz = 1;
        }
        if (nz) atomicOr(&cnt, 1);
        __syncthreads();
        if (threadIdx.x == 0) *flag = (cnt == 0) ? 1 : 0;
    }
}

// ---- K1: MFMA GEMM [hb | out] = bf16(x) @ [Wp | Ws], fused attdot epilogue ----
// 256 thr / 4 waves / 64 rows per block. All global traffic coalesced:
//  - x-tile (32 KB contiguous) staged to LDS via float4, XOR-swizzled writes
//  - B loads lane-contiguous 16B (fragment-ordered Wt)
//  - out written via f32 LDS tile (unioned with x-stage) as float4
// C/D layout: col=lane&15, row=(lane>>4)*4+reg  [learn_hip m89].
#define HBP 136    // bf16 LDS h-tile pitch (68 words)
#define SKP 132    // f32 LDS skip-tile pitch
__global__ __launch_bounds__(256) void k_gemm(const float* __restrict__ x,
                                              const unsigned short* __restrict__ Wt,
                                              const float* __restrict__ att,
                                              unsigned short* __restrict__ hb,
                                              float* __restrict__ as_,
                                              float* __restrict__ ad_,
                                              float* __restrict__ out) {
    __shared__ float SK[64 * SKP];            // 33792 B; first acts as x-stage
    __shared__ unsigned short HB[64 * HBP];   // 17408 B
    char* XSc = (char*)SK;

    const int tid = threadIdx.x;
    const int rw  = tid >> 6;           // wave id == row tile
    const int l   = tid & 63;
    const int l15 = l & 15;
    const int lq  = l >> 4;

    // ---- stage x[64][128] f32 -> LDS, coalesced read, swizzled write ----
    {
        int d = tid * 16;
        #pragma unroll
        for (int it = 0; it < 8; ++it, d += 4096) {
            int row = d >> 9, col = d & 511;
            int grow = blockIdx.x * 64 + row;
            if (grow > N_NODES - 1) grow = N_NODES - 1;
            float4 v = *(const float4*)((const char*)x + (size_t)grow * 512 + col);
            *(float4*)(XSc + (row << 9) + (col ^ ((row & 7) << 4))) = v;
        }
    }
    __syncthreads();

    // ---- A fragments from LDS (2-way-conflict-free ds_read_b128) ----
    const int rl = rw * 16 + l15;
    const int sw = (rl & 7) << 4;
    bf16x8 afr[4];
    #pragma unroll
    for (int ks = 0; ks < 4; ++ks) {
        int c0 = ks * 128 + lq * 32;
        float4 u0 = *(const float4*)(XSc + (rl << 9) + (c0 ^ sw));
        float4 u1 = *(const float4*)(XSc + (rl << 9) + ((c0 + 16) ^ sw));
        bf16x8 a;
        a[0] = (short)f2bf(u0.x); a[1] = (short)f2bf(u0.y);
        a[2] = (short)f2bf(u0.z); a[3] = (short)f2bf(u0.w);
        a[4] = (short)f2bf(u1.x); a[5] = (short)f2bf(u1.y);
        a[6] = (short)f2bf(u1.z); a[7] = (short)f2bf(u1.w);
        afr[ks] = a;
    }
    __syncthreads();   // x-stage dead; SK reusable for skip tile

    f32x4 acc[16];
    #pragma unroll
    for (int nf = 0; nf < 16; ++nf) acc[nf] = (f32x4)(0.0f);

    #pragma unroll
    for (int nf = 0; nf < 16; ++nf) {
        #pragma unroll
        for (int ks = 0; ks < 4; ++ks) {
            bf16x8 b = *(const bf16x8*)(Wt + ((((nf * 4 + ks) << 6) + l) << 3));
            acc[nf] = __builtin_amdgcn_mfma_f32_16x16x32_bf16(afr[ks], b, acc[nf], 0, 0, 0);
        }
    }

    // ---- write result tiles to LDS ----
    #pragma unroll
    for (int nf = 0; nf < 8; ++nf) {
        #pragma unroll
        for (int q = 0; q < 4; ++q) {
            int r2 = rw * 16 + lq * 4 + q;
            HB[r2 * HBP + nf * 16 + l15] = f2bf(acc[nf][q]);
        }
    }
    #pragma unroll
    for (int nf = 8; nf < 16; ++nf) {
        #pragma unroll
        for (int q = 0; q < 4; ++q) {
            int r2 = rw * 16 + lq * 4 + q;
            SK[r2 * SKP + (nf - 8) * 16 + l15] = acc[nf][q];
        }
    }
    __syncthreads();

    // fused attdot: 256 threads = 64 rows x 4 heads
    {
        int rl2 = tid >> 2, hd = tid & 3;
        const unsigned* HBu = (const unsigned*)HB;
        const float* a1 = att + hd * 2 * DHEAD;
        const float* a2 = a1 + DHEAD;
        float s1 = 0.0f, s2 = 0.0f;
        #pragma unroll
        for (int j = 0; j < 16; ++j) {
            unsigned u = HBu[rl2 * (HBP / 2) + hd * 16 + j];
            float lo = bf2f((unsigned short)(u & 0xffff));
            float hi = bf2f((unsigned short)(u >> 16));
            s1 += lo * a1[2 * j] + hi * a1[2 * j + 1];
            s2 += lo * a2[2 * j] + hi * a2[2 * j + 1];
        }
        int rowg = blockIdx.x * 64 + rl2;     // as_/ad_ padded to 50048
        as_[(size_t)rowg * 4 + hd] = s1;
        ad_[(size_t)rowg * 4 + hd] = s2;
    }

    // hb store, 16B/lane (hb padded to 50048 rows)
    {
        const unsigned* HBu = (const unsigned*)HB;
        #pragma unroll
        for (int it = 0; it < 4; ++it) {
            int idx = it * 256 + tid;        // 0..1023
            int row = idx >> 4, g = idx & 15;
            int wb = row * (HBP / 2) + g * 4;
            uint4 v;
            v.x = HBu[wb]; v.y = HBu[wb + 1]; v.z = HBu[wb + 2]; v.w = HBu[wb + 3];
            *(uint4*)(hb + ((size_t)(blockIdx.x * 64 + row)) * DOUT + g * 8) = v;
        }
    }
    // out (skip) store, 16B/lane, guarded
    {
        #pragma unroll
        for (int it = 0; it < 8; ++it) {
            int idx = it * 256 + tid;        // 0..2047
            int row = idx >> 5, c4 = idx & 31;
            int rowg = blockIdx.x * 64 + row;
            if (rowg < N_NODES) {
                float4 v = *(const float4*)&SK[row * SKP + c4 * 4];
                *(float4*)(out + (size_t)rowg * DOUT + c4 * 4) = v;
            }
        }
    }
}

// ---- K2a: bucket partition. 256 blocks x 3125 edges. Payload (dl<<16)|src. ----
__global__ __launch_bounds__(256) void k_part(const int* __restrict__ ei,
                                              const int* __restrict__ flag,
                                              int* __restrict__ bucketCnt,
                                              unsigned* __restrict__ payload) {
    __shared__ int hist[NB];
    __shared__ int curs[NB];
    const int t = threadIdx.x;
    const int base = blockIdx.x * 3125;
    const int isI64 = *flag;

    for (int i = t; i < NB; i += 256) hist[i] = 0;
    __syncthreads();
    for (int i = t; i < 3125; i += 256) {
        int src, dst;
        load_edge(ei, isI64, base + i, src, dst);
        if ((unsigned)dst < N_NODES) atomicAdd(&hist[dst >> 8], 1);
    }
    __syncthreads();
    for (int i = t; i < NB; i += 256)
        curs[i] = atomicAdd(&bucketCnt[i], hist[i]);
    __syncthreads();
    for (int i = t; i < 3125; i += 256) {
        int src, dst;
        load_edge(ei, isI64, base + i, src, dst);
        if ((unsigned)src >= N_NODES || (unsigned)dst >= N_NODES) continue;
        int b = dst >> 8;
        int pos = atomicAdd(&curs[b], 1);
        if (pos < CAP)
            payload[((size_t)b << 13) + pos] = ((unsigned)(dst & 255) << 16) | (unsigned)src;
    }
}

// ---- K2b: per-bucket CSR build: deg/ofs (bucket-based) + srcs scatter ----
__global__ __launch_bounds__(256) void k_csr(const int* __restrict__ bucketCnt,
                                             const unsigned* __restrict__ payload,
                                             int* __restrict__ deg,
                                             int* __restrict__ ofs,
                                             int* __restrict__ srcs) {
    __shared__ int h[256];
    __shared__ int cur[256];
    __shared__ int sc[256];
    const int b = blockIdx.x;
    const int t = threadIdx.x;
    int cnt = bucketCnt[b];
    if (cnt > CAP) cnt = CAP;
    const unsigned* __restrict__ pl = payload + ((size_t)b << 13);

    h[t] = 0;
    __syncthreads();
    for (int i = t; i < cnt; i += 256) atomicAdd(&h[pl[i] >> 16], 1);
    __syncthreads();
    int v = h[t];
    sc[t] = v;
    __syncthreads();
    #pragma unroll
    for (int off = 1; off < 256; off <<= 1) {
        int u = (t >= off) ? sc[t - off] : 0;
        __syncthreads();
        sc[t] += u;
        __syncthreads();
    }
    int ex = sc[t] - v;              // exclusive local prefix
    cur[t] = ex;
    int n = (b << 8) + t;
    if (n < N_NODES) { deg[n] = v; ofs[n] = (b << 13) + ex; }
    __syncthreads();
    for (int i = t; i < cnt; i += 256) {
        unsigned p = pl[i];
        int pos = atomicAdd(&cur[p >> 16], 1);
        srcs[((size_t)b << 13) + pos] = (int)(p & 0xFFFFu);
    }
}

// ---- K3: per-node gather: 2 nodes/block, 64 thr/node, uint col-pair loads ----
__global__ __launch_bounds__(128) void k_gat(const int* __restrict__ ofs,
                                             const int* __restrict__ deg,
                                             const int* __restrict__ srcs,
                                             const float* __restrict__ as_,
                                             const float* __restrict__ ad_,
                                             const unsigned short* __restrict__ hb,
                                             float* __restrict__ out) {
    __shared__ float EL[2][NHEAD * ELP];   // 2 x 4.2 KB
    __shared__ int   SRC[2][DMAX];         // 2 x 1 KB

    const int sub = threadIdx.x >> 6;      // node slot in block
    const int k   = threadIdx.x & 63;
    const int hd  = k >> 4;
    const int l16 = k & 15;
    const int n = blockIdx.x * 2 + sub;    // 25000*2 == 50000 exactly
    const int o = ofs[n];
    const int d = deg[n];
    const unsigned* __restrict__ hbu = (const unsigned*)hb;
    float* ELn = EL[sub];
    int*   SRCn = SRC[sub];

    int fast = __syncthreads_and(d <= DMAX);   // block-uniform branch

    if (fast) {
        const float4 adv4 = *(const float4*)(ad_ + (size_t)n * 4);
        for (int e = k; e < d; e += 64) {
            int s = srcs[o + e];
            SRCn[e] = s;
            float4 a4 = *(const float4*)(as_ + (size_t)s * 4);
            float e0 = a4.x + adv4.x, e1 = a4.y + adv4.y;
            float e2 = a4.z + adv4.z, e3 = a4.w + adv4.w;
            ELn[0 * ELP + e] = (e0 > 0.0f) ? e0 : NEG_SLOPE * e0;
            ELn[1 * ELP + e] = (e1 > 0.0f) ? e1 : NEG_SLOPE * e1;
            ELn[2 * ELP + e] = (e2 > 0.0f) ? e2 : NEG_SLOPE * e2;
            ELn[3 * ELP + e] = (e3 > 0.0f) ? e3 : NEG_SLOPE * e3;
        }
        __syncthreads();
        float m = -3.4e38f;
        for (int i = l16; i < d; i += 16) m = fmaxf(m, ELn[hd * ELP + i]);
        #pragma unroll
        for (int off = 8; off; off >>= 1) m = fmaxf(m, __shfl_xor(m, off));
        float den = 0.0f;
        for (int i = l16; i < d; i += 16) {
            float p = __expf(ELn[hd * ELP + i] - m);
            ELn[hd * ELP + i] = p;
            den += p;
        }
        #pragma unroll
        for (int off = 8; off; off >>= 1) den += __shfl_xor(den, off);
        __syncthreads();
        float num0 = 0.0f, num1 = 0.0f;
        for (int i = 0; i < d; ++i) {
            float p = ELn[hd * ELP + i];
            int s = SRCn[i];
            unsigned u = hbu[(size_t)s * (DOUT / 2) + k];
            num0 = fmaf(p, bf2f((unsigned short)(u & 0xffff)), num0);
            num1 = fmaf(p, bf2f((unsigned short)(u >> 16)), num1);
        }
        float inv = 1.0f / (den + EPS_F);
        float2* op = (float2*)(out + (size_t)n * DOUT + 2 * k);
        float2 sk = *op;
        *op = make_float2(num0 * inv + sk.x, num1 * inv + sk.y);
    } else {
        const float adv = ad_[(size_t)n * 4 + hd];
        float m = -3.4e38f;
        for (int i = 0; i < d; ++i) {
            float el = as_[(size_t)srcs[o + i] * 4 + hd] + adv;
            el = (el > 0.0f) ? el : NEG_SLOPE * el;
            m = fmaxf(m, el);
        }
        float den = 0.0f, num0 = 0.0f, num1 = 0.0f;
        for (int i = 0; i < d; ++i) {
            int s = srcs[o + i];
            float el = as_[(size_t)s * 4 + hd] + adv;
            el = (el > 0.0f) ? el : NEG_SLOPE * el;
            float p = __expf(el - m);
            den += p;
            unsigned u = hbu[(size_t)s * (DOUT / 2) + k];
            num0 = fmaf(p, bf2f((unsigned short)(u & 0xffff)), num0);
            num1 = fmaf(p, bf2f((unsigned short)(u >> 16)), num1);
        }
        float inv = 1.0f / (den + EPS_F);
        float2* op = (float2*)(out + (size_t)n * DOUT + 2 * k);
        float2 sk = *op;
        *op = make_float2(num0 * inv + sk.x, num1 * inv + sk.y);
    }
}

extern "C" void kernel_launch(void* const* d_in, const int* in_sizes, int n_in,
                              void* d_out, int out_size, void* d_ws, size_t ws_size,
                              hipStream_t stream) {
    const float* x   = (const float*)d_in[0];
    const float* Wp  = (const float*)d_in[1];
    const float* att = (const float*)d_in[2];
    const float* Ws  = (const float*)d_in[3];
    const int*   ei  = (const int*)d_in[4];
    float* out = (float*)d_out;

    char* ws = (char*)d_ws;
    unsigned short* hb        = (unsigned short*)(ws);              // 12,812,288 B (50048 rows)
    unsigned short* Wt        = (unsigned short*)(ws + 12812288);   // 65,536 B
    float*          as_       = (float*)(ws + 12877824);            // 800,768 B
    float*          ad_       = (float*)(ws + 13678592);            // 800,768 B
    int*            deg       = (int*)(ws + 14479360);              // 200,704 B
    int*            ofs       = (int*)(ws + 14680064);              // 200,704 B
    unsigned*       payload   = (unsigned*)(ws + 14880768);         // 6,422,528 B
    int*            srcs      = (int*)(ws + 21303296);              // 6,422,528 B
    int*            bucketCnt = (int*)(ws + 27725824);              // 1,024 B
    int*            flag      = (int*)(ws + 27726848);

    hipMemsetAsync(bucketCnt, 0, NB * 4, stream);

    k_prep<<<257, 128, 0, stream>>>(Wp, Ws, ei, Wt, flag);
    k_gemm<<<(N_NODES + 63) / 64, 256, 0, stream>>>(x, Wt, att, hb, as_, ad_, out);
    k_part<<<256, 256, 0, stream>>>(ei, flag, bucketCnt, payload);
    k_csr<<<NB, 256, 0, stream>>>(bucketCnt, payload, deg, ofs, srcs);
    k_gat<<<N_NODES / 2, 128, 0, stream>>>(ofs, deg, srcs, as_, ad_, hb, out);
}